// Round 15
// baseline (205.202 us; speedup 1.0000x reference)
//
#include <hip/hip_runtime.h>
#include <stdint.h>

typedef __attribute__((ext_vector_type(8))) short short8;
typedef __attribute__((ext_vector_type(4))) float floatx4;
typedef __attribute__((ext_vector_type(16))) float floatx16;

__device__ inline unsigned short f2bf(float x) {
  union { float f; unsigned int u; } v; v.f = x;
  unsigned int r = v.u + 0x7FFFu + ((v.u >> 16) & 1u);  // RNE
  return (unsigned short)(r >> 16);
}

// ---------------------------------------------------------------------------
// pack_all: one dispatch does both packs. (verified, unchanged)
//   blocks [0,4096):    A_bf16[4096][2048] = bf16([x | h])
//   blocks [4096,6144): Wt_perm[4096][2048] = bf16(W^T) gate-interleaved:
//                       R = (h>>5)*128 + ((h>>4)&1)*64 + g*16 + (h&15)
// ---------------------------------------------------------------------------
__global__ void pack_all(const float* __restrict__ x, const float* __restrict__ h,
                         const float* __restrict__ wi, const float* __restrict__ wh,
                         unsigned short* __restrict__ A,
                         unsigned short* __restrict__ Wt) {
  int bid = blockIdx.x;
  int t = threadIdx.x;
  if (bid < 4096) {
    int idx = bid * 256 + t;
    int row = idx >> 8;
    int kc  = (idx & 255) << 3;
    const float* src = (kc < 1024) ? (x + (size_t)row * 1024 + kc)
                                   : (h + (size_t)row * 1024 + (kc - 1024));
    float4 a = ((const float4*)src)[0];
    float4 b = ((const float4*)src)[1];
    uint4 o;
    o.x = f2bf(a.x) | ((unsigned)f2bf(a.y) << 16);
    o.y = f2bf(a.z) | ((unsigned)f2bf(a.w) << 16);
    o.z = f2bf(b.x) | ((unsigned)f2bf(b.y) << 16);
    o.w = f2bf(b.z) | ((unsigned)f2bf(b.w) << 16);
    *(uint4*)(A + (size_t)row * 2048 + kc) = o;
  } else {
    __shared__ float tile[64][65];
    int b2 = bid - 4096;
    int kt = b2 & 31;
    int nt = b2 >> 5;
    int k0 = kt << 6, n0 = nt << 6;
    const float* src = (k0 < 1024) ? (wi + (size_t)k0 * 4096)
                                   : (wh + (size_t)(k0 - 1024) * 4096);
    int c4 = (t & 15) << 2, rr = t >> 4;
#pragma unroll
    for (int p = 0; p < 4; ++p) {
      int kk = rr + p * 16;
      float4 v = *(const float4*)(src + (size_t)kk * 4096 + n0 + c4);
      tile[kk][c4 + 0] = v.x; tile[kk][c4 + 1] = v.y;
      tile[kk][c4 + 2] = v.z; tile[kk][c4 + 3] = v.w;
    }
    __syncthreads();
    int k8 = (t & 7) << 3, nn = t >> 3;
#pragma unroll
    for (int p = 0; p < 2; ++p) {
      int n = n0 + nn + p * 32;          // global N index (gate*1024 + h)
      int hh = n & 1023, g = n >> 10;
      int R = ((hh >> 5) << 7) + (((hh >> 4) & 1) << 6) + (g << 4) + (hh & 15);
      int nl = nn + p * 32;
      uint4 o;
      o.x = f2bf(tile[k8 + 0][nl]) | ((unsigned)f2bf(tile[k8 + 1][nl]) << 16);
      o.y = f2bf(tile[k8 + 2][nl]) | ((unsigned)f2bf(tile[k8 + 3][nl]) << 16);
      o.z = f2bf(tile[k8 + 4][nl]) | ((unsigned)f2bf(tile[k8 + 5][nl]) << 16);
      o.w = f2bf(tile[k8 + 6][nl]) | ((unsigned)f2bf(tile[k8 + 7][nl]) << 16);
      *(uint4*)(Wt + (size_t)R * 2048 + k0 + k8) = o;
    }
  }
}

// ---------------------------------------------------------------------------
// gemm_lstm R14: R13 (32x32x16 shape) + stride-8-quad conflict fix.
//   R13 regressed 76->87 us with BANK_CONFLICT 0 -> 2^23 (= 4 cyc on every
//   ds_read_b128). Diagnosis from the R7-vs-R13 contrast: rows are bank-
//   invisible (128 B stride), and the conflicting lane-set is the stride-8
//   quad {l,l+8,l+16,l+24} — in R13 all four share kq2 AND key lane&7 ->
//   identical phys chunk -> 4-way. R7 was free because its quads mixed kq.
//   FIX: fold row bits 3:4 into the XOR key on BOTH sides:
//     key2(row) = (row&7) ^ ((row>>3)&3)
//   store: cs = ((tid&7) ^ (sr&7) ^ ((sr>>3)&3)) << 4   (p-invariant)
//   read:  keyc = (lane&7) ^ ((lane>>3)&3)              (wm/+32-invariant)
//   Every stride-8 quad now gets 4 distinct chunks; 16-lane groups <=2-way.
//   Everything else = R13 (which passed absmax -> layout algebra verified).
// ---------------------------------------------------------------------------
__device__ inline void gl_lds16(const void* g, void* l) {
  __builtin_amdgcn_global_load_lds(
      (const __attribute__((address_space(1))) void*)g,
      (__attribute__((address_space(3))) void*)l, 16, 0, 0);
}

__device__ inline float sigm(float x)  { return 1.0f / (1.0f + __expf(-x)); }
__device__ inline float tanhx(float x) { return 2.0f / (1.0f + __expf(-2.0f * x)) - 1.0f; }

__global__ void __launch_bounds__(256, 4) gemm_lstm(
    const unsigned short* __restrict__ A,
    const unsigned short* __restrict__ Bt,
    const float* __restrict__ ct,
    const float* __restrict__ bi,
    const float* __restrict__ bh,
    float* __restrict__ out) {
  constexpr int K = 2048;
  __shared__ char AsB[128 * 128];  // 128 rows x 64 bf16 (128 B)
  __shared__ char BsB[128 * 128];
  const int tid  = threadIdx.x;
  const int lane = tid & 63;
  const int wave = tid >> 6;
  const int wm = wave >> 1, wn = wave & 1;

  // ---- XCD supertile swizzle (bijection on [0,1024)) ----
  const int bid = blockIdx.x;
  const int g  = bid & 7;
  const int s  = bid >> 3;
  const int bx = (g << 2) + (s & 3);
  const int by = ((s >> 4) << 2) + ((s >> 2) & 3);
  const int m0 = by << 7;
  const int n0 = bx << 7;   // linear row block in permuted W
  const int h0 = bx << 5;   // 32 h per block

  // epilogue lane mapping + bias preload
  const int c32  = lane & 31;           // C/D column
  const int kq2  = lane >> 5;           // k-chunk / C-row-offset select
  const int h    = h0 + (wn << 4) + (c32 & 15);
  float bias[4];
#pragma unroll
  for (int j = 0; j < 4; ++j) bias[j] = bi[j * 1024 + h] + bh[j * 1024 + h];

  // ---- staging: uniform base (SGPR) + ONE shared per-lane offset ----
  // key2(row) = (row&7) ^ ((row>>3)&3), p-invariant (row+32 -> +4 mod 4 = 0)
  const int sr = tid >> 3;                              // LDS row 0..31 (+p*32)
  const int cs = ((tid & 7) ^ (sr & 7) ^ ((sr >> 3) & 3)) << 4;
  const unsigned voff = (unsigned)sr * 4096u + (unsigned)cs;
  const char* aBase = (const char*)A  + (size_t)m0 * 4096;
  const char* bBase = (const char*)Bt + (size_t)n0 * 4096;
  char* aD = AsB + tid * 16;
  char* bD = BsB + tid * 16;

  floatx16 acc[2][2] = {};
  // LDS fragment bases; read key = key2(row), row = (w<<6)+c32 [+32]
  const int keyc = (lane & 7) ^ ((lane >> 3) & 3);
  const char* aR0 = AsB + ((wm << 6) + c32) * 128;   // i=0 base; i=1: +4096
  const char* bR0 = BsB + ((wn << 6) + c32) * 128;   // j=0 base; j=1: +4096

  for (int ks = 0; ks < K; ks += 64) {
    const char* aIt = aBase + ks * 2;   // uniform
    const char* bIt = bBase + ks * 2;   // uniform
#pragma unroll
    for (int p = 0; p < 4; ++p) gl_lds16(aIt + p * 131072 + voff, aD + p * 4096);
#pragma unroll
    for (int p = 0; p < 4; ++p) gl_lds16(bIt + p * 131072 + voff, bD + p * 4096);
    __syncthreads();
#pragma unroll
    for (int st = 0; st < 4; ++st) {
      const int ofs = (((st << 1) + kq2) ^ keyc) << 4;   // 16B chunk in 64-k row
      short8 a0 = *(const short8*)(aR0 + ofs);
      short8 a1 = *(const short8*)(aR0 + 4096 + ofs);
      short8 b0 = *(const short8*)(bR0 + ofs);
      short8 b1 = *(const short8*)(bR0 + 4096 + ofs);
      acc[0][0] = __builtin_amdgcn_mfma_f32_32x32x16_bf16(a0, b0, acc[0][0], 0, 0, 0);
      acc[0][1] = __builtin_amdgcn_mfma_f32_32x32x16_bf16(a0, b1, acc[0][1], 0, 0, 0);
      acc[1][0] = __builtin_amdgcn_mfma_f32_32x32x16_bf16(a1, b0, acc[1][0], 0, 0, 0);
      acc[1][1] = __builtin_amdgcn_mfma_f32_32x32x16_bf16(a1, b1, acc[1][1], 0, 0, 0);
    }
    __syncthreads();
  }

  // ---- fused LSTM epilogue (32x32 C/D layout + partner-lane gate swap) ----
  const bool lo = (c32 < 16);
  float cv[2][8];
#pragma unroll
  for (int i2 = 0; i2 < 2; ++i2)
#pragma unroll
    for (int r = 0; r < 8; ++r) {
      int rr = lo ? r : r + 8;
      int rloc = (rr & 3) + ((rr >> 2) << 3) + (kq2 << 2);
      int row = m0 + (wm << 6) + i2 * 32 + rloc;
      cv[i2][r] = ct[(size_t)row * 1024 + h];
    }
#pragma unroll
  for (int i2 = 0; i2 < 2; ++i2) {
#pragma unroll
    for (int r = 0; r < 8; ++r) {
      // send the half the partner needs; receive the half we need
      float s0 = lo ? acc[i2][0][r + 8] : acc[i2][0][r];
      float s1 = lo ? acc[i2][1][r + 8] : acc[i2][1][r];
      float e0 = __shfl_xor(s0, 16);
      float e1 = __shfl_xor(s1, 16);
      float a0 = lo ? acc[i2][0][r] : acc[i2][0][r + 8];
      float a1 = lo ? acc[i2][1][r] : acc[i2][1][r + 8];
      // lane c<16 holds gates {0,2}; partner holds {1,3} for the same h
      float ig = lo ? a0 : e0;
      float fg = lo ? e0 : a0;
      float gg = lo ? a1 : e1;
      float og = lo ? e1 : a1;
      int rr = lo ? r : r + 8;
      int rloc = (rr & 3) + ((rr >> 2) << 3) + (kq2 << 2);
      int row = m0 + (wm << 6) + i2 * 32 + rloc;
      size_t o = (size_t)row * 1024 + h;
      float iv = sigm(ig + bias[0]);
      float fv = sigm(fg + bias[1]);
      float gv = tanhx(gg + bias[2]);
      float ov = sigm(og + bias[3]);
      float cn = fv * cv[i2][r] + iv * gv;
      out[o] = ov * tanhx(cn);
      out[4194304 + o] = cn;
    }
  }
}

// ---------------------------------------------------------------------------
extern "C" void kernel_launch(void* const* d_in, const int* in_sizes, int n_in,
                              void* d_out, int out_size, void* d_ws, size_t ws_size,
                              hipStream_t stream) {
  const float* x  = (const float*)d_in[0];
  const float* ht = (const float*)d_in[1];
  const float* ct = (const float*)d_in[2];
  const float* wi = (const float*)d_in[3];
  const float* wh = (const float*)d_in[4];
  const float* bi = (const float*)d_in[5];
  const float* bh = (const float*)d_in[6];
  float* out = (float*)d_out;

  char* ws = (char*)d_ws;
  unsigned short* Abf = (unsigned short*)ws;                 // 16 MiB
  unsigned short* Wbf = (unsigned short*)(ws + (16u << 20)); // 16 MiB

  pack_all<<<6144, 256, 0, stream>>>(x, ht, wi, wh, Abf, Wbf);
  gemm_lstm<<<1024, 256, 0, stream>>>(Abf, Wbf, ct, bi, bh, out);
}

// Round 16
// 193.409 us; speedup vs baseline: 1.0610x; 1.0610x over previous
//
#include <hip/hip_runtime.h>
#include <stdint.h>

typedef __attribute__((ext_vector_type(8))) short short8;
typedef __attribute__((ext_vector_type(4))) float floatx4;

__device__ inline unsigned short f2bf(float x) {
  union { float f; unsigned int u; } v; v.f = x;
  unsigned int r = v.u + 0x7FFFu + ((v.u >> 16) & 1u);  // RNE
  return (unsigned short)(r >> 16);
}

// ---------------------------------------------------------------------------
// pack_all: one dispatch does both packs. (verified)
//   blocks [0,4096):    A_bf16[4096][2048] = bf16([x | h])
//   blocks [4096,6144): Wt_perm[4096][2048] = bf16(W^T) gate-interleaved:
//                       R = (h>>5)*128 + ((h>>4)&1)*64 + g*16 + (h&15)
// ---------------------------------------------------------------------------
__global__ void pack_all(const float* __restrict__ x, const float* __restrict__ h,
                         const float* __restrict__ wi, const float* __restrict__ wh,
                         unsigned short* __restrict__ A,
                         unsigned short* __restrict__ Wt) {
  int bid = blockIdx.x;
  int t = threadIdx.x;
  if (bid < 4096) {
    int idx = bid * 256 + t;
    int row = idx >> 8;
    int kc  = (idx & 255) << 3;
    const float* src = (kc < 1024) ? (x + (size_t)row * 1024 + kc)
                                   : (h + (size_t)row * 1024 + (kc - 1024));
    float4 a = ((const float4*)src)[0];
    float4 b = ((const float4*)src)[1];
    uint4 o;
    o.x = f2bf(a.x) | ((unsigned)f2bf(a.y) << 16);
    o.y = f2bf(a.z) | ((unsigned)f2bf(a.w) << 16);
    o.z = f2bf(b.x) | ((unsigned)f2bf(b.y) << 16);
    o.w = f2bf(b.z) | ((unsigned)f2bf(b.w) << 16);
    *(uint4*)(A + (size_t)row * 2048 + kc) = o;
  } else {
    __shared__ float tile[64][65];
    int b2 = bid - 4096;
    int kt = b2 & 31;
    int nt = b2 >> 5;
    int k0 = kt << 6, n0 = nt << 6;
    const float* src = (k0 < 1024) ? (wi + (size_t)k0 * 4096)
                                   : (wh + (size_t)(k0 - 1024) * 4096);
    int c4 = (t & 15) << 2, rr = t >> 4;
#pragma unroll
    for (int p = 0; p < 4; ++p) {
      int kk = rr + p * 16;
      float4 v = *(const float4*)(src + (size_t)kk * 4096 + n0 + c4);
      tile[kk][c4 + 0] = v.x; tile[kk][c4 + 1] = v.y;
      tile[kk][c4 + 2] = v.z; tile[kk][c4 + 3] = v.w;
    }
    __syncthreads();
    int k8 = (t & 7) << 3, nn = t >> 3;
#pragma unroll
    for (int p = 0; p < 2; ++p) {
      int n = n0 + nn + p * 32;          // global N index (gate*1024 + h)
      int hh = n & 1023, g = n >> 10;
      int R = ((hh >> 5) << 7) + (((hh >> 4) & 1) << 6) + (g << 4) + (hh & 15);
      int nl = nn + p * 32;
      uint4 o;
      o.x = f2bf(tile[k8 + 0][nl]) | ((unsigned)f2bf(tile[k8 + 1][nl]) << 16);
      o.y = f2bf(tile[k8 + 2][nl]) | ((unsigned)f2bf(tile[k8 + 3][nl]) << 16);
      o.z = f2bf(tile[k8 + 4][nl]) | ((unsigned)f2bf(tile[k8 + 5][nl]) << 16);
      o.w = f2bf(tile[k8 + 6][nl]) | ((unsigned)f2bf(tile[k8 + 7][nl]) << 16);
      *(uint4*)(Wt + (size_t)R * 2048 + k0 + k8) = o;
    }
  }
}

// ---------------------------------------------------------------------------
// gemm_lstm: R7 FINAL — best of 12 measured variants (75.4-76.7 us gemm,
// 194.2-194.9 us total).
//   128x128 tile, BK=64, 4 waves, 2-barrier K-loop, global_load_lds w=16,
//   XOR-8 both-sides swizzle (0 conflicts), XCD supertile swizzle,
//   launch_bounds(256,4) -> 4 blocks/CU (1024 blocks = 1 clean epoch),
//   fused LSTM epilogue (gate = j via pack permutation).
//   Session record: 8-phase m201 ports (x3), counted-lgkm pipeline,
//   2-barrier 256^2, 256x128 geometry, occupancy 1-4 blocks/CU, and
//   32x32x16 shape (+conflict fix: BANK_CONFLICT 8.4M -> 0 but 85.5 us)
//   all land 76-87 us. This kernel = 905 TF ~= documented m97-family
//   plain-HIP ceiling; escape requires hand-asm-grade scheduling that
//   did not reproduce at HIP source level in this harness.
// ---------------------------------------------------------------------------
__device__ inline void gl_lds16(const void* g, void* l) {
  __builtin_amdgcn_global_load_lds(
      (const __attribute__((address_space(1))) void*)g,
      (__attribute__((address_space(3))) void*)l, 16, 0, 0);
}

__device__ inline float sigm(float x)  { return 1.0f / (1.0f + __expf(-x)); }
__device__ inline float tanhx(float x) { return 2.0f / (1.0f + __expf(-2.0f * x)) - 1.0f; }

__global__ void __launch_bounds__(256, 4) gemm_lstm(
    const unsigned short* __restrict__ A,
    const unsigned short* __restrict__ Bt,
    const float* __restrict__ ct,
    const float* __restrict__ bi,
    const float* __restrict__ bh,
    float* __restrict__ out) {
  constexpr int K = 2048;
  __shared__ char AsB[128 * 128];  // 128 rows x 64 bf16 (128 B)
  __shared__ char BsB[128 * 128];
  const int tid  = threadIdx.x;
  const int lane = tid & 63;
  const int wave = tid >> 6;
  const int wm = wave >> 1, wn = wave & 1;

  // ---- XCD supertile swizzle (bijection on [0,1024)) ----
  const int bid = blockIdx.x;
  const int g  = bid & 7;
  const int s  = bid >> 3;
  const int bx = (g << 2) + (s & 3);
  const int by = ((s >> 4) << 2) + ((s >> 2) & 3);
  const int m0 = by << 7;
  const int n0 = bx << 7;   // linear row block in permuted W
  const int h0 = bx << 5;   // 32 h per block

  // epilogue lane mapping + bias preload (latency hidden by K-loop)
  const int er = (lane >> 4) << 2;
  const int ec = lane & 15;
  const int h  = h0 + (wn << 4) + ec;
  float bias[4];
#pragma unroll
  for (int j = 0; j < 4; ++j) bias[j] = bi[j * 1024 + h] + bh[j * 1024 + h];

  // ---- staging: uniform base (SGPR) + ONE shared per-lane offset ----
  const int sr = tid >> 3;                              // LDS row 0..31 (+p*32)
  const int cs = ((tid & 7) ^ (sr & 7)) << 4;           // XOR-swizzled source chunk
  const unsigned voff = (unsigned)sr * 4096u + (unsigned)cs;  // per-lane, invariant
  const char* aBase = (const char*)A  + (size_t)m0 * 4096;    // row = 4096 B
  const char* bBase = (const char*)Bt + (size_t)n0 * 4096;
  char* aD = AsB + tid * 16;
  char* bD = BsB + tid * 16;

  floatx4 acc[4][4] = {};
  // LDS fragment bases (loop-invariant; f*16 rows -> +f*2048 immediate)
  const int rA = (wm << 6) + (lane & 15);
  const int rB = (wn << 6) + (lane & 15);
  const int keyc = lane & 7;
  const int kq   = lane >> 4;
  const char* aF0 = AsB + rA * 128 + ((kq ^ keyc) << 4);
  const char* aF1 = AsB + rA * 128 + (((4 + kq) ^ keyc) << 4);
  const char* bF0 = BsB + rB * 128 + ((kq ^ keyc) << 4);
  const char* bF1 = BsB + rB * 128 + (((4 + kq) ^ keyc) << 4);

  for (int ks = 0; ks < K; ks += 64) {
    const char* aIt = aBase + ks * 2;   // uniform
    const char* bIt = bBase + ks * 2;   // uniform
#pragma unroll
    for (int p = 0; p < 4; ++p) gl_lds16(aIt + p * 131072 + voff, aD + p * 4096);
#pragma unroll
    for (int p = 0; p < 4; ++p) gl_lds16(bIt + p * 131072 + voff, bD + p * 4096);
    __syncthreads();
    {
      short8 af[4], bfr[4];
#pragma unroll
      for (int f = 0; f < 4; ++f) {
        af[f]  = *(const short8*)(aF0 + f * 2048);
        bfr[f] = *(const short8*)(bF0 + f * 2048);
      }
#pragma unroll
      for (int i = 0; i < 4; ++i)
#pragma unroll
        for (int j = 0; j < 4; ++j)
          acc[i][j] = __builtin_amdgcn_mfma_f32_16x16x32_bf16(af[i], bfr[j], acc[i][j], 0, 0, 0);
    }
    {
      short8 af[4], bfr[4];
#pragma unroll
      for (int f = 0; f < 4; ++f) {
        af[f]  = *(const short8*)(aF1 + f * 2048);
        bfr[f] = *(const short8*)(bF1 + f * 2048);
      }
#pragma unroll
      for (int i = 0; i < 4; ++i)
#pragma unroll
        for (int j = 0; j < 4; ++j)
          acc[i][j] = __builtin_amdgcn_mfma_f32_16x16x32_bf16(af[i], bfr[j], acc[i][j], 0, 0, 0);
    }
    __syncthreads();
  }

  // ---- fused LSTM epilogue: batch ct loads, then lane-local gates ----
  float cv[4][4];
#pragma unroll
  for (int i = 0; i < 4; ++i)
#pragma unroll
    for (int rg = 0; rg < 4; ++rg) {
      int row = m0 + (wm << 6) + i * 16 + er + rg;
      cv[i][rg] = ct[(size_t)row * 1024 + h];
    }
#pragma unroll
  for (int i = 0; i < 4; ++i) {
#pragma unroll
    for (int rg = 0; rg < 4; ++rg) {
      int row = m0 + (wm << 6) + i * 16 + er + rg;
      size_t o = (size_t)row * 1024 + h;
      float iv = sigm(acc[i][0][rg] + bias[0]);
      float fv = sigm(acc[i][1][rg] + bias[1]);
      float gv = tanhx(acc[i][2][rg] + bias[2]);
      float ov = sigm(acc[i][3][rg] + bias[3]);
      float cn = fv * cv[i][rg] + iv * gv;
      out[o] = ov * tanhx(cn);
      out[4194304 + o] = cn;
    }
  }
}

// ---------------------------------------------------------------------------
extern "C" void kernel_launch(void* const* d_in, const int* in_sizes, int n_in,
                              void* d_out, int out_size, void* d_ws, size_t ws_size,
                              hipStream_t stream) {
  const float* x  = (const float*)d_in[0];
  const float* ht = (const float*)d_in[1];
  const float* ct = (const float*)d_in[2];
  const float* wi = (const float*)d_in[3];
  const float* wh = (const float*)d_in[4];
  const float* bi = (const float*)d_in[5];
  const float* bh = (const float*)d_in[6];
  float* out = (float*)d_out;

  char* ws = (char*)d_ws;
  unsigned short* Abf = (unsigned short*)ws;                 // 16 MiB
  unsigned short* Wbf = (unsigned short*)(ws + (16u << 20)); // 16 MiB

  pack_all<<<6144, 256, 0, stream>>>(x, ht, wi, wh, Abf, Wbf);
  gemm_lstm<<<1024, 256, 0, stream>>>(Abf, Wbf, ct, bi, bh, out);
}